// Round 10
// baseline (383.230 us; speedup 1.0000x reference)
//
#include <hip/hip_runtime.h>

#define VQ_K 512
#define VQ_D 64
#define VQ_N (32 * 64 * 64)   // B*H*W = 131072
#define CH_STRIDE 4096        // H*W
#define B_STRIDE  262144      // C*H*W
#define ROWDW 68              // LDS row stride in dwords (272B, 16B-aligned)
#define WIN 1.0e-3f           // rescore window >> ~3e-5 approx-error tail

typedef float f32x4 __attribute__((ext_vector_type(4)));
typedef short s16x8 __attribute__((ext_vector_type(8)));   // 8 bf16 (4 VGPRs)

__device__ __forceinline__ unsigned int bf16_rn(float f) {
    unsigned int u = __float_as_uint(f);
    return (u + 0x7fffu + ((u >> 16) & 1u)) >> 16;   // RN-even; no NaNs in data
}
__device__ __forceinline__ float bf16_to_f(unsigned int h) {
    return __uint_as_float(h << 16);
}

// Pre-pass over the codebook: squared norms (same fmaf chain as R1-R7) and
// bf16 limb decomposition packed for direct B-fragment loads.
// cbl dword layout per code k: [0..31] = h-limb dim pairs, [32..63] = l-limb.
__global__ void cb_prep_kernel(const float* __restrict__ cb,
                               float* __restrict__ cbsq,
                               unsigned int* __restrict__ cbl) {
    int k = blockIdx.x * 64 + threadIdx.x;   // grid 8x64 = 512 exactly
    const f32x4* row = (const f32x4*)(cb + k * VQ_D);
    float s = 0.f;
    #pragma unroll
    for (int c = 0; c < 16; ++c) {
        f32x4 v = row[c];
        s = fmaf(v.x, v.x, s);
        s = fmaf(v.y, v.y, s);
        s = fmaf(v.z, v.z, s);
        s = fmaf(v.w, v.w, s);
        unsigned int hx = bf16_rn(v.x), hy = bf16_rn(v.y);
        unsigned int hz = bf16_rn(v.z), hw = bf16_rn(v.w);
        unsigned int lx = bf16_rn(v.x - bf16_to_f(hx));
        unsigned int ly = bf16_rn(v.y - bf16_to_f(hy));
        unsigned int lz = bf16_rn(v.z - bf16_to_f(hz));
        unsigned int lw = bf16_rn(v.w - bf16_to_f(hw));
        cbl[k * 64 + 2 * c]          = hx | (hy << 16);
        cbl[k * 64 + 2 * c + 1]      = hz | (hw << 16);
        cbl[k * 64 + 32 + 2 * c]     = lx | (ly << 16);
        cbl[k * 64 + 32 + 2 * c + 1] = lz | (lw << 16);
    }
    cbsq[k] = s;
}

// Exact fp32 distance, bit-identical formula/association to R1 (absmax 0.0
// across 7 rounds): 4 accumulators over d%4 ascending, (d0+d1)+(d2+d3),
// (insq + csq) - 2*dot.
__device__ __forceinline__ float rescore_exact(const float* __restrict__ cbrow,
                                               const float* __restrict__ fxrow,
                                               float insq, float csq) {
    float d0 = 0.f, d1 = 0.f, d2 = 0.f, d3 = 0.f;
    #pragma unroll
    for (int ch = 0; ch < 16; ++ch) {
        f32x4 a = *(const f32x4*)(fxrow + ch * 4);
        f32x4 b = *(const f32x4*)(cbrow + ch * 4);
        d0 = fmaf(a.x, b.x, d0);
        d1 = fmaf(a.y, b.y, d1);
        d2 = fmaf(a.z, b.z, d2);
        d3 = fmaf(a.w, b.w, d3);
    }
    float dot = (d0 + d1) + (d2 + d3);
    return (insq + csq) - 2.f * dot;
}

// R8 post-mortem: split-bf16 MFMA dists are right up to ~1e-5 (few argmin
// flips at near-ties -> absmax 244). Fix: MFMA is only a FILTER.
//   Phase A: approx dists -> per-position global approx min (value).
//   Phase B: rerun; candidates with approx <= gmin+WIN rescored exactly in
//   fp32 (R1 formula); lexicographic (dist,idx) argmin over candidates.
// Containment: |approx-exact| <= eps << WIN, so np's argmin always qualifies;
// ties vs non-candidates impossible since WIN > 2*eps.
// Block = 256 thr = 4 waves; wave w owns codes [w*128,(w+1)*128).
__global__ __launch_bounds__(256) void vq_mfma_kernel(
        const float* __restrict__ x,
        const float* __restrict__ cb,
        const float* __restrict__ cbsq,
        const unsigned int* __restrict__ cbl,
        int* __restrict__ out) {
    __shared__ __align__(16) unsigned int alds[64 * ROWDW];  // bf16 limbs, 17408 B
    __shared__ __align__(16) float        fx[64 * ROWDW];    // fp32 x tile, 17408 B
    __shared__ float insqL[64];
    __shared__ float gminL[64];
    __shared__ float sred[4][64];
    __shared__ int   sredi[4][64];

    int t    = threadIdx.x;
    int pos  = t & 63;
    int w    = t >> 6;
    int c    = t & 15;        // MFMA: A row / B col / D col
    int hi   = (t & 63) >> 4; // MFMA k-group / D row-group
    int n0   = blockIdx.x * 64;
    int b    = n0 >> 12;
    int p0   = n0 & 4095;
    const float* xrow = x + b * B_STRIDE + p0;

    // ---- Stage: fp32 tile + bf16 limb tile. Thread (pos,w) covers dims
    // {2w+8r, 2w+8r+1}; global reads coalesced (fixed dim, 64 consecutive pos).
    #pragma unroll
    for (int r = 0; r < 8; ++r) {
        int d0 = 2 * w + 8 * r;
        float c0 = xrow[d0 * CH_STRIDE + pos];
        float c1 = xrow[(d0 + 1) * CH_STRIDE + pos];
        fx[pos * ROWDW + d0]     = c0;
        fx[pos * ROWDW + d0 + 1] = c1;
        unsigned int h0 = bf16_rn(c0), h1 = bf16_rn(c1);
        unsigned int l0 = bf16_rn(c0 - bf16_to_f(h0));
        unsigned int l1 = bf16_rn(c1 - bf16_to_f(h1));
        alds[pos * ROWDW + (d0 >> 1)]      = h0 | (h1 << 16);
        alds[pos * ROWDW + 32 + (d0 >> 1)] = l0 | (l1 << 16);
    }
    __syncthreads();

    // ================= Phase A: approx min value per position =============
    float bestA[16];
    #pragma unroll
    for (int s = 0; s < 16; ++s) bestA[s] = 3.4e38f;

    #pragma unroll
    for (int pt = 0; pt < 4; ++pt) {
        const unsigned int* arow = alds + (pt * 16 + c) * ROWDW + hi * 4;
        s16x8 ah0 = *(const s16x8*)(arow);        // xh dims hi*8..+7
        s16x8 ah1 = *(const s16x8*)(arow + 16);   // xh dims 32+hi*8..+7
        s16x8 al0 = *(const s16x8*)(arow + 32);   // xl k-chunk 0
        s16x8 al1 = *(const s16x8*)(arow + 48);   // xl k-chunk 1
        #pragma unroll 1
        for (int ct = 0; ct < 8; ++ct) {
            int code = (w << 7) + (ct << 4) + c;
            const unsigned int* bp = cbl + code * 64 + hi * 4;
            s16x8 bh0 = *(const s16x8*)(bp);
            s16x8 bh1 = *(const s16x8*)(bp + 16);
            s16x8 bl0 = *(const s16x8*)(bp + 32);
            s16x8 bl1 = *(const s16x8*)(bp + 48);
            float csq = cbsq[code];
            f32x4 a0 = {0.f, 0.f, 0.f, 0.f}, a1 = {0.f, 0.f, 0.f, 0.f};
            a0 = __builtin_amdgcn_mfma_f32_16x16x32_bf16(ah0, bh0, a0, 0, 0, 0);
            a0 = __builtin_amdgcn_mfma_f32_16x16x32_bf16(ah0, bl0, a0, 0, 0, 0);
            a0 = __builtin_amdgcn_mfma_f32_16x16x32_bf16(al0, bh0, a0, 0, 0, 0);
            a0 = __builtin_amdgcn_mfma_f32_16x16x32_bf16(al0, bl0, a0, 0, 0, 0);
            a1 = __builtin_amdgcn_mfma_f32_16x16x32_bf16(ah1, bh1, a1, 0, 0, 0);
            a1 = __builtin_amdgcn_mfma_f32_16x16x32_bf16(ah1, bl1, a1, 0, 0, 0);
            a1 = __builtin_amdgcn_mfma_f32_16x16x32_bf16(al1, bh1, a1, 0, 0, 0);
            a1 = __builtin_amdgcn_mfma_f32_16x16x32_bf16(al1, bl1, a1, 0, 0, 0);
            #pragma unroll
            for (int r = 0; r < 4; ++r) {
                float dist = fmaf(-2.f, a0[r] + a1[r], csq);
                bestA[pt * 4 + r] = fminf(bestA[pt * 4 + r], dist);
            }
        }
    }
    // min over the 16 lanes of each hi-group
    #pragma unroll
    for (int mask = 1; mask <= 8; mask <<= 1) {
        #pragma unroll
        for (int s = 0; s < 16; ++s)
            bestA[s] = fminf(bestA[s], __shfl_xor(bestA[s], mask));
    }
    if (c == 0) {
        #pragma unroll
        for (int s = 0; s < 16; ++s)
            sred[w][(s >> 2) * 16 + hi * 4 + (s & 3)] = bestA[s];
    }
    __syncthreads();
    if (t < 64) {
        float g = sred[0][t];
        #pragma unroll
        for (int j = 1; j < 4; ++j) g = fminf(g, sred[j][t]);
        gminL[t] = g;
        // insq with R1's exact association (needed by rescore)
        const float* fr = fx + t * ROWDW;
        float s0 = 0.f, s1 = 0.f, s2 = 0.f, s3 = 0.f;
        #pragma unroll
        for (int ch = 0; ch < 16; ++ch) {
            f32x4 v = *(const f32x4*)(fr + ch * 4);
            s0 = fmaf(v.x, v.x, s0);
            s1 = fmaf(v.y, v.y, s1);
            s2 = fmaf(v.z, v.z, s2);
            s3 = fmaf(v.w, v.w, s3);
        }
        insqL[t] = (s0 + s1) + (s2 + s3);
    }
    __syncthreads();

    // ================= Phase B: window candidates + exact rescore =========
    float eb[16];
    int   ei[16];
    float win[16];
    #pragma unroll
    for (int s = 0; s < 16; ++s) {
        eb[s] = 3.4e38f;
        ei[s] = 0;
        win[s] = gminL[(s >> 2) * 16 + hi * 4 + (s & 3)] + WIN;
    }

    #pragma unroll
    for (int pt = 0; pt < 4; ++pt) {
        const unsigned int* arow = alds + (pt * 16 + c) * ROWDW + hi * 4;
        s16x8 ah0 = *(const s16x8*)(arow);
        s16x8 ah1 = *(const s16x8*)(arow + 16);
        s16x8 al0 = *(const s16x8*)(arow + 32);
        s16x8 al1 = *(const s16x8*)(arow + 48);
        #pragma unroll 1
        for (int ct = 0; ct < 8; ++ct) {
            int code = (w << 7) + (ct << 4) + c;
            const unsigned int* bp = cbl + code * 64 + hi * 4;
            s16x8 bh0 = *(const s16x8*)(bp);
            s16x8 bh1 = *(const s16x8*)(bp + 16);
            s16x8 bl0 = *(const s16x8*)(bp + 32);
            s16x8 bl1 = *(const s16x8*)(bp + 48);
            float csq = cbsq[code];
            f32x4 a0 = {0.f, 0.f, 0.f, 0.f}, a1 = {0.f, 0.f, 0.f, 0.f};
            a0 = __builtin_amdgcn_mfma_f32_16x16x32_bf16(ah0, bh0, a0, 0, 0, 0);
            a0 = __builtin_amdgcn_mfma_f32_16x16x32_bf16(ah0, bl0, a0, 0, 0, 0);
            a0 = __builtin_amdgcn_mfma_f32_16x16x32_bf16(al0, bh0, a0, 0, 0, 0);
            a0 = __builtin_amdgcn_mfma_f32_16x16x32_bf16(al0, bl0, a0, 0, 0, 0);
            a1 = __builtin_amdgcn_mfma_f32_16x16x32_bf16(ah1, bh1, a1, 0, 0, 0);
            a1 = __builtin_amdgcn_mfma_f32_16x16x32_bf16(ah1, bl1, a1, 0, 0, 0);
            a1 = __builtin_amdgcn_mfma_f32_16x16x32_bf16(al1, bh1, a1, 0, 0, 0);
            a1 = __builtin_amdgcn_mfma_f32_16x16x32_bf16(al1, bl1, a1, 0, 0, 0);
            #pragma unroll
            for (int r = 0; r < 4; ++r) {
                float dist = fmaf(-2.f, a0[r] + a1[r], csq);
                int s = pt * 4 + r;
                if (dist <= win[s]) {      // rare (~1 per position total)
                    int ppos = pt * 16 + hi * 4 + r;
                    float e = rescore_exact(cb + code * VQ_D,
                                            fx + ppos * ROWDW,
                                            insqL[ppos], csq);
                    if (e < eb[s] || (e == eb[s] && code < ei[s])) {
                        eb[s] = e; ei[s] = code;
                    }
                }
            }
        }
    }
    // lexicographic (dist, idx) min over the 16 lanes of each hi-group —
    // associative+commutative, preserves np.argmin first-occurrence.
    #pragma unroll
    for (int mask = 1; mask <= 8; mask <<= 1) {
        #pragma unroll
        for (int s = 0; s < 16; ++s) {
            float od = __shfl_xor(eb[s], mask);
            int   oi = __shfl_xor(ei[s], mask);
            if (od < eb[s] || (od == eb[s] && oi < ei[s])) {
                eb[s] = od; ei[s] = oi;
            }
        }
    }
    if (c == 0) {
        #pragma unroll
        for (int s = 0; s < 16; ++s) {
            int p = (s >> 2) * 16 + hi * 4 + (s & 3);
            sred[w][p]  = eb[s];
            sredi[w][p] = ei[s];
        }
    }
    __syncthreads();

    // Cross-wave reduce, ascending w (= ascending code range), strict <.
    if (t < 64) {
        float bb = sred[0][t];
        int   ii = sredi[0][t];
        #pragma unroll
        for (int j = 1; j < 4; ++j) {
            float d = sred[j][t];
            if (d < bb) { bb = d; ii = sredi[j][t]; }
        }
        out[n0 + t] = ii;
    }
}

extern "C" void kernel_launch(void* const* d_in, const int* in_sizes, int n_in,
                              void* d_out, int out_size, void* d_ws, size_t ws_size,
                              hipStream_t stream) {
    const float* x  = (const float*)d_in[0];   // [32,64,64,64] fp32
    const float* cb = (const float*)d_in[1];   // [512,64] fp32
    int* out = (int*)d_out;                    // [32,64,64] int32
    // ws layout: cbsq [512 f32] | cbl [512*64 u32]  = 133120 B total
    float* cbsq        = (float*)d_ws;
    unsigned int* cbl  = (unsigned int*)d_ws + 512;

    cb_prep_kernel<<<VQ_K / 64, 64, 0, stream>>>(cb, cbsq, cbl);
    vq_mfma_kernel<<<VQ_N / 64, 256, 0, stream>>>(x, cb, cbsq, cbl, out);
}